// Round 3
// baseline (416.966 us; speedup 1.0000x reference)
//
#include <hip/hip_runtime.h>
#include <math.h>

// GraphAttentionLayer:
//   Wh = X @ W ; f = Wh @ a1 ; g = Wh @ a2
//   attention = softmax(leaky_relu(f[:,None] + g[None,:]), axis=1)
// Reassociated: f = X @ (W@a1), g = X @ (W@a2).  adj is unused by the reference.
// leaky_relu is monotone => row max = lrelu(f_i + max(g)).
//
// 3-dispatch pipeline (gmax fused into k_fg via order-preserving-uint atomicMax):
//   k_wa:   wa1/wa2 = W@a1, W@a2; also re-inits the gmax atomic cell (poisoned
//           each iteration by the harness) — kernel boundary orders it before k_fg.
//   k_fg:   f,g per row; per-block max(g) -> atomicMax (device scope, 2048 ops).
//   k_attn: per-row softmax, exp computed once into 32 VGPRs, nontemporal stores.

static constexpr float ALPHA = 0.2f;
static constexpr int N    = 8192;
static constexpr int FIN  = 512;
static constexpr int FOUT = 256;

typedef float v4f __attribute__((ext_vector_type(4)));

__device__ __forceinline__ float lrelu(float x) {
    // for 0<ALPHA<1: lrelu(x) == max(x, ALPHA*x)
    return fmaxf(x, ALPHA * x);
}

// Order-preserving encode of float into uint: enc(a) < enc(b) <=> a < b.
__device__ __forceinline__ unsigned enc_f32(float x) {
    unsigned b = __float_as_uint(x);
    return (b & 0x80000000u) ? ~b : (b | 0x80000000u);
}
__device__ __forceinline__ float dec_f32(unsigned u) {
    unsigned b = (u & 0x80000000u) ? (u & 0x7FFFFFFFu) : ~u;
    return __uint_as_float(b);
}

// ---------------- Kernel A: wa1[k] = sum_j W[k,j]*a[j]; wa2[k] = sum_j W[k,j]*a[FOUT+j]
// grid = FIN blocks x 64 threads (one wave per W row). Block 0 re-inits gmax cell.
__global__ void k_wa(const float* __restrict__ W, const float* __restrict__ a,
                     float* __restrict__ wa1, float* __restrict__ wa2,
                     unsigned* __restrict__ gmax_u) {
    const int k    = blockIdx.x;
    const int lane = threadIdx.x;
    if (k == 0 && lane == 0) *gmax_u = 0u;  // 0 <= enc(x) for all finite/inf x
    const float* row = W + (size_t)k * FOUT;
    float s1 = 0.0f, s2 = 0.0f;
    for (int j = lane; j < FOUT; j += 64) {
        const float w = row[j];
        s1 += w * a[j];
        s2 += w * a[FOUT + j];
    }
    #pragma unroll
    for (int off = 32; off > 0; off >>= 1) {
        s1 += __shfl_down(s1, off, 64);
        s2 += __shfl_down(s2, off, 64);
    }
    if (lane == 0) { wa1[k] = s1; wa2[k] = s2; }
}

// ---------------- Kernel B: f[i] = dot(X[i,:], wa1); g[i] = dot(X[i,:], wa2)
// one wave per row; 4 waves/block; per-block g-max -> atomicMax(gmax_u).
// grid is exactly N/4 blocks (8192 rows / 4 waves), no partial blocks.
__global__ __launch_bounds__(256) void k_fg(const float* __restrict__ X,
                                            const float* __restrict__ wa1,
                                            const float* __restrict__ wa2,
                                            float* __restrict__ f,
                                            float* __restrict__ g,
                                            unsigned* __restrict__ gmax_u) {
    const int gid  = blockIdx.x * blockDim.x + threadIdx.x;
    const int row  = gid >> 6;
    const int lane = threadIdx.x & 63;
    const int wid  = threadIdx.x >> 6;
    const float4* x4  = (const float4*)(X + (size_t)row * FIN);
    const float4* w14 = (const float4*)wa1;
    const float4* w24 = (const float4*)wa2;
    float s1 = 0.0f, s2 = 0.0f;
    #pragma unroll
    for (int k4 = lane; k4 < (FIN >> 2); k4 += 64) {
        const float4 v  = x4[k4];
        const float4 w1 = w14[k4];
        const float4 w2 = w24[k4];
        s1 += v.x*w1.x + v.y*w1.y + v.z*w1.z + v.w*w1.w;
        s2 += v.x*w2.x + v.y*w2.y + v.z*w2.z + v.w*w2.w;
    }
    #pragma unroll
    for (int off = 32; off > 0; off >>= 1) {
        s1 += __shfl_down(s1, off, 64);
        s2 += __shfl_down(s2, off, 64);
    }
    __shared__ float smax[4];
    if (lane == 0) {
        f[row] = s1;
        g[row] = s2;
        smax[wid] = s2;
    }
    __syncthreads();
    if (threadIdx.x == 0) {
        const float bm = fmaxf(fmaxf(smax[0], smax[1]), fmaxf(smax[2], smax[3]));
        atomicMax(gmax_u, enc_f32(bm));  // device-scope by default
    }
}

// ---------------- Kernel C: per-row softmax of lrelu(f_i + g_j)
// block per row, 256 threads. Each thread owns exactly 8 float4 (32 cols):
// exp values computed ONCE into 32 VGPRs across the reduction, then scaled
// and written with nontemporal stores (output is never re-read).
__global__ __launch_bounds__(256) void k_attn(const float* __restrict__ f,
                                              const float* __restrict__ g,
                                              const unsigned* __restrict__ gmax_u,
                                              float* __restrict__ out) {
    const int i = blockIdx.x;
    const float fi = f[i];
    const float m  = lrelu(fi + dec_f32(*gmax_u));

    const float4* g4   = (const float4*)g;
    v4f*          out4 = (v4f*)(out + (size_t)i * N);
    constexpr int n4 = N >> 2;        // 2048
    constexpr int PT = n4 / 256;      // 8 float4 per thread = 32 VGPRs

    float4 p[PT];
    float sum = 0.0f;
    #pragma unroll
    for (int t = 0; t < PT; ++t) {
        const int j = threadIdx.x + t * 256;
        const float4 gv = g4[j];
        float4 e;
        e.x = __expf(lrelu(fi + gv.x) - m);
        e.y = __expf(lrelu(fi + gv.y) - m);
        e.z = __expf(lrelu(fi + gv.z) - m);
        e.w = __expf(lrelu(fi + gv.w) - m);
        sum += (e.x + e.y) + (e.z + e.w);
        p[t] = e;
    }

    __shared__ float sm[4];
    #pragma unroll
    for (int off = 32; off > 0; off >>= 1) sum += __shfl_down(sum, off, 64);
    if ((threadIdx.x & 63) == 0) sm[threadIdx.x >> 6] = sum;
    __syncthreads();
    const float total = (sm[0] + sm[1]) + (sm[2] + sm[3]);
    const float inv = 1.0f / total;

    #pragma unroll
    for (int t = 0; t < PT; ++t) {
        const int j = threadIdx.x + t * 256;
        v4f o;
        o.x = p[t].x * inv;
        o.y = p[t].y * inv;
        o.z = p[t].z * inv;
        o.w = p[t].w * inv;
        __builtin_nontemporal_store(o, &out4[j]);
    }
}

extern "C" void kernel_launch(void* const* d_in, const int* in_sizes, int n_in,
                              void* d_out, int out_size, void* d_ws, size_t ws_size,
                              hipStream_t stream) {
    const float* X = (const float*)d_in[0];   // (N, FIN)
    // d_in[1] = adj — unused by the reference computation
    const float* W = (const float*)d_in[2];   // (FIN, FOUT)
    const float* a = (const float*)d_in[3];   // (2*FOUT, 1)
    float* out = (float*)d_out;               // (N, N)

    float* ws       = (float*)d_ws;
    float* wa1      = ws;                 // FIN
    float* wa2      = ws + FIN;           // FIN
    float* f        = ws + 2 * FIN;       // N
    float* g        = ws + 2 * FIN + N;   // N
    unsigned* gmaxu = (unsigned*)(ws + 2 * FIN + 2 * N); // 1 (order-encoded)

    k_wa  <<<FIN, 64, 0, stream>>>(W, a, wa1, wa2, gmaxu);
    k_fg  <<<N / 4, 256, 0, stream>>>(X, wa1, wa2, f, g, gmaxu);
    k_attn<<<N, 256, 0, stream>>>(f, g, gmaxu, out);
}

// Round 4
// 396.408 us; speedup vs baseline: 1.0519x; 1.0519x over previous
//
#include <hip/hip_runtime.h>
#include <math.h>

// GraphAttentionLayer:
//   Wh = X @ W ; f = Wh @ a1 ; g = Wh @ a2
//   attention = softmax(leaky_relu(f[:,None] + g[None,:]), axis=1)
// Reassociated: f = X @ (W@a1), g = X @ (W@a2).  adj is unused by the reference.
// leaky_relu is monotone => row max = lrelu(f_i + max(g)).
//
// 3-dispatch pipeline, NO cross-block atomics (round-3 post-mortem: 2048
// same-address device-scope atomicMax cost +18 µs — serialized at the
// coherence point):
//   k_wa:   wa1/wa2 = W@a1, W@a2.
//   k_fg:   f,g per row (one wave per row).
//   k_attn: each block already reads ALL of g, so it computes max(g) itself
//           from the in-register g values, then exps in-register (computed
//           once), then scaled nontemporal stores. No k_gmax kernel.

static constexpr float ALPHA = 0.2f;
static constexpr int N    = 8192;
static constexpr int FIN  = 512;
static constexpr int FOUT = 256;

typedef float v4f __attribute__((ext_vector_type(4)));

__device__ __forceinline__ float lrelu(float x) {
    // for 0<ALPHA<1: lrelu(x) == max(x, ALPHA*x)
    return fmaxf(x, ALPHA * x);
}

// ---------------- Kernel A: wa1[k] = sum_j W[k,j]*a[j]; wa2[k] = sum_j W[k,j]*a[FOUT+j]
// grid = FIN blocks x 64 threads (one wave per W row)
__global__ void k_wa(const float* __restrict__ W, const float* __restrict__ a,
                     float* __restrict__ wa1, float* __restrict__ wa2) {
    const int k    = blockIdx.x;
    const int lane = threadIdx.x;
    const float* row = W + (size_t)k * FOUT;
    float s1 = 0.0f, s2 = 0.0f;
    for (int j = lane; j < FOUT; j += 64) {
        const float w = row[j];
        s1 += w * a[j];
        s2 += w * a[FOUT + j];
    }
    #pragma unroll
    for (int off = 32; off > 0; off >>= 1) {
        s1 += __shfl_down(s1, off, 64);
        s2 += __shfl_down(s2, off, 64);
    }
    if (lane == 0) { wa1[k] = s1; wa2[k] = s2; }
}

// ---------------- Kernel B: f[i] = dot(X[i,:], wa1); g[i] = dot(X[i,:], wa2)
// one wave per row; 4 waves/block; grid exactly N/4 blocks.
__global__ __launch_bounds__(256) void k_fg(const float* __restrict__ X,
                                            const float* __restrict__ wa1,
                                            const float* __restrict__ wa2,
                                            float* __restrict__ f,
                                            float* __restrict__ g) {
    const int gid  = blockIdx.x * blockDim.x + threadIdx.x;
    const int row  = gid >> 6;
    const int lane = threadIdx.x & 63;
    const float4* x4  = (const float4*)(X + (size_t)row * FIN);
    const float4* w14 = (const float4*)wa1;
    const float4* w24 = (const float4*)wa2;
    float s1 = 0.0f, s2 = 0.0f;
    #pragma unroll
    for (int k4 = lane; k4 < (FIN >> 2); k4 += 64) {
        const float4 v  = x4[k4];
        const float4 w1 = w14[k4];
        const float4 w2 = w24[k4];
        s1 += v.x*w1.x + v.y*w1.y + v.z*w1.z + v.w*w1.w;
        s2 += v.x*w2.x + v.y*w2.y + v.z*w2.z + v.w*w2.w;
    }
    #pragma unroll
    for (int off = 32; off > 0; off >>= 1) {
        s1 += __shfl_down(s1, off, 64);
        s2 += __shfl_down(s2, off, 64);
    }
    if (lane == 0) { f[row] = s1; g[row] = s2; }
}

// ---------------- Kernel C: per-row softmax of lrelu(f_i + g_j)
// block per row, 256 threads. Each thread owns exactly 8 float4 (32 cols).
// Phase 1: load g into 32 VGPRs, block-reduce max(g)  (block reads ALL of g).
// Phase 2: exps computed in-register (once), block-reduce sum.
// Phase 3: scale + nontemporal stores (output never re-read).
__global__ __launch_bounds__(256) void k_attn(const float* __restrict__ f,
                                              const float* __restrict__ g,
                                              float* __restrict__ out) {
    const int i = blockIdx.x;
    const float fi = f[i];

    const float4* g4   = (const float4*)g;
    v4f*          out4 = (v4f*)(out + (size_t)i * N);
    constexpr int n4 = N >> 2;        // 2048
    constexpr int PT = n4 / 256;      // 8 float4 per thread = 32 VGPRs

    // Phase 1: load g, track per-thread max
    float4 p[PT];
    float pm = -INFINITY;
    #pragma unroll
    for (int t = 0; t < PT; ++t) {
        const int j = threadIdx.x + t * 256;
        const float4 gv = g4[j];
        p[t] = gv;
        pm = fmaxf(fmaxf(pm, fmaxf(gv.x, gv.y)), fmaxf(gv.z, gv.w));
    }
    __shared__ float smx[4];
    __shared__ float sms[4];
    #pragma unroll
    for (int off = 32; off > 0; off >>= 1) pm = fmaxf(pm, __shfl_down(pm, off, 64));
    if ((threadIdx.x & 63) == 0) smx[threadIdx.x >> 6] = pm;
    __syncthreads();
    const float gmax = fmaxf(fmaxf(smx[0], smx[1]), fmaxf(smx[2], smx[3]));
    const float m = lrelu(fi + gmax);   // row max of e (lrelu monotone)

    // Phase 2: exps in-register, computed once
    float sum = 0.0f;
    #pragma unroll
    for (int t = 0; t < PT; ++t) {
        float4 e;
        e.x = __expf(lrelu(fi + p[t].x) - m);
        e.y = __expf(lrelu(fi + p[t].y) - m);
        e.z = __expf(lrelu(fi + p[t].z) - m);
        e.w = __expf(lrelu(fi + p[t].w) - m);
        sum += (e.x + e.y) + (e.z + e.w);
        p[t] = e;
    }
    #pragma unroll
    for (int off = 32; off > 0; off >>= 1) sum += __shfl_down(sum, off, 64);
    if ((threadIdx.x & 63) == 0) sms[threadIdx.x >> 6] = sum;
    __syncthreads();
    const float total = (sms[0] + sms[1]) + (sms[2] + sms[3]);
    const float inv = 1.0f / total;

    // Phase 3: scale + streaming store
    #pragma unroll
    for (int t = 0; t < PT; ++t) {
        const int j = threadIdx.x + t * 256;
        v4f o;
        o.x = p[t].x * inv;
        o.y = p[t].y * inv;
        o.z = p[t].z * inv;
        o.w = p[t].w * inv;
        __builtin_nontemporal_store(o, &out4[j]);
    }
}

extern "C" void kernel_launch(void* const* d_in, const int* in_sizes, int n_in,
                              void* d_out, int out_size, void* d_ws, size_t ws_size,
                              hipStream_t stream) {
    const float* X = (const float*)d_in[0];   // (N, FIN)
    // d_in[1] = adj — unused by the reference computation
    const float* W = (const float*)d_in[2];   // (FIN, FOUT)
    const float* a = (const float*)d_in[3];   // (2*FOUT, 1)
    float* out = (float*)d_out;               // (N, N)

    float* ws  = (float*)d_ws;
    float* wa1 = ws;                 // FIN
    float* wa2 = ws + FIN;           // FIN
    float* f   = ws + 2 * FIN;       // N
    float* g   = ws + 2 * FIN + N;   // N

    k_wa  <<<FIN, 64, 0, stream>>>(W, a, wa1, wa2);
    k_fg  <<<N / 4, 256, 0, stream>>>(X, wa1, wa2, f, g);
    k_attn<<<N, 256, 0, stream>>>(f, g, out);
}